// Round 9
// baseline (163.183 us; speedup 1.0000x reference)
//
#include <hip/hip_runtime.h>
#include <stdint.h>

#define N_ROWS 8192
#define D_DIM  1024
#define NEG_BIG -1e30f
#define NCHUNK 8
#define CHUNK_J 1024
#define NTILE 32            // 32 j-cols per tile, 32 tiles per chunk
#define BUFSZ (32 * 1024)   // 32 rows x 1024 B, swizzled (16B-slot XOR) layout

typedef __attribute__((ext_vector_type(16))) float f32x16;
typedef __attribute__((ext_vector_type(8)))  int   i32x8;
typedef __attribute__((ext_vector_type(2)))  long  long2_t;

// log2(e) * 10 : exp(10v - 10) = exp2(v*C - C)
#define EXPC 14.4269504089f
#define EXPV(v) exp2f(fmaf((v), EXPC, -EXPC))

// branchless sorted insert of v into descending 5-list, med3 form (5 ops)
#define INS5(b0,b1,b2,b3,b4,v) {                        \
    float _n4 = __builtin_amdgcn_fmed3f(b3, (v), b4);   \
    float _n3 = __builtin_amdgcn_fmed3f(b2, (v), b3);   \
    float _n2 = __builtin_amdgcn_fmed3f(b1, (v), b2);   \
    float _n1 = __builtin_amdgcn_fmed3f(b0, (v), b1);   \
    b0 = fmaxf(b0, (v)); b1 = _n1; b2 = _n2; b3 = _n3; b4 = _n4; }

// f32 -> OCP e4m3fn, RNE, with denormals. |x| <= ~1 here (normalized rows).
static __device__ inline uint32_t f2e4m3(float x) {
    uint32_t u = __float_as_uint(x);
    uint32_t s = (u >> 24) & 0x80u;
    uint32_t a = u & 0x7fffffffu;
    uint32_t e = a >> 23;
    uint32_t out;
    if (e >= 121u) {
        uint32_t mant = a & 0x7fffffu;
        uint32_t comb = ((e - 120u) << 3) | (mant >> 20);
        uint32_t rem  = mant & 0xfffffu;
        comb += (rem > 0x80000u) || ((rem == 0x80000u) && (comb & 1u));
        out = comb;
    } else {
        float scl = __uint_as_float(a) * 512.0f;
        out = (uint32_t)(int)rintf(scl);
    }
    return s | out;
}

// ---------------- K1: row-normalize f32 -> fp8 e4m3 ----------------
__global__ __launch_bounds__(256) void norm_kernel(const float* __restrict__ z,
                                                   uint8_t* __restrict__ zn8) {
    int wave = threadIdx.x >> 6;
    int lane = threadIdx.x & 63;
    int row  = blockIdx.x * 4 + wave;
    const float* zr = z + (size_t)row * D_DIM;
    float4 c[4];
    float ss = 0.f;
#pragma unroll
    for (int i = 0; i < 4; ++i) {
        c[i] = *(const float4*)(zr + i * 256 + lane * 4);
        ss += c[i].x*c[i].x + c[i].y*c[i].y + c[i].z*c[i].z + c[i].w*c[i].w;
    }
#pragma unroll
    for (int m = 1; m < 64; m <<= 1) ss += __shfl_xor(ss, m);
    float scale = 1.0f / fmaxf(sqrtf(ss), 1e-12f);
    uint8_t* zo = zn8 + (size_t)row * D_DIM;
#pragma unroll
    for (int i = 0; i < 4; ++i) {
        uint32_t d = f2e4m3(c[i].x * scale)
                   | (f2e4m3(c[i].y * scale) << 8)
                   | (f2e4m3(c[i].z * scale) << 16)
                   | (f2e4m3(c[i].w * scale) << 24);
        *(uint32_t*)(zo + i * 256 + lane * 4) = d;
    }
}

// ---------------- K2: fused fp8 sim via scale-MFMA K=64 ----------------
// grid: 64 i-blocks (128 rows, 32/wave) x 8 j-chunks (1024 cols).
// Swapped MFMA: A = streamed j-tile (LDS), B = resident i-rows held in
// AGPRs ("a" pin) -- gfx950 MFMA sources A/B from AGPR directly, freeing
// the arch-VGPR half for the deferred-epilogue state (no spills).
// LDS swizzle: 16B-slot s of row jr holds global slot s^(jr&7) (full 3-bit
// involution). Read: 4 per-lane base pointers + immediate offsets.
// Deferred epilogue: per tile, reduce+mask accs into ONE f32x16 (svp); the
// 128-VALU INS5/EXPV chain of tile t-1 runs during tile t's read/MFMA phase.
// svp starts at NEG_BIG: EXPV(NEG_BIG)=0, INS5(NEG_BIG)=no-op -> uniform loop.
__global__ __launch_bounds__(256, 2) void sim_kernel(const uint8_t* __restrict__ zn8,
                                                     float* __restrict__ pstats) {
    __shared__ __align__(16) char lds[2 * BUFSZ];
    const int tid  = threadIdx.x;
    const int w    = tid >> 6;
    const int l    = tid & 63;
    const int r32  = l & 31;
    const int h    = l >> 5;
    const int f3   = r32 & 7;
    const int ib   = blockIdx.x >> 3;
    const int ch   = blockIdx.x & 7;
    const int i0w  = ib * 128 + w * 32;
    const int j0c  = ch * CHUNK_J;
    const int i_lane = i0w + r32;
    const int diag_jt = (ch == (ib >> 3)) ? ((ib & 7) * 4 + w) : -1;

    // 4 per-lane LDS read base pointers
    const int b0f = f3 & 1, b1f = (f3 >> 1) & 1, b2f = f3 >> 2;
    const int e0 = r32 * 1024 + (b2f << 6) + ((h ^ b1f) << 5) + (b0f << 4);
    const char* a00 = lds + e0;          // even m, low 16B
    const char* a01 = lds + (e0 ^ 16);   // even m, high 16B
    const char* a10 = lds + (e0 ^ 64);   // odd m, low 16B
    const char* a11 = lds + (e0 ^ 80);   // odd m, high 16B

    // prologue: stage tile 0 into buffer 0
#pragma unroll
    for (int u = 0; u < 8; ++u) {
        int jr = w * 8 + u;
        const uint8_t* src = zn8 + (size_t)(j0c + jr) * D_DIM + ((l ^ (jr & 7)) << 4);
        char* dst = lds + jr * 1024;
        __builtin_amdgcn_global_load_lds(
            (const __attribute__((address_space(1))) uint32_t*)src,
            (__attribute__((address_space(3))) uint32_t*)dst, 16, 0, 0);
    }

    // resident B-operand: lane holds col i_lane; bres[m] = k bytes [m*64+h*32, +32)
    i32x8 bres[16];
    {
        const uint8_t* rp = zn8 + (size_t)i_lane * D_DIM + h * 32;
#pragma unroll
        for (int m = 0; m < 16; ++m) {
            *(long2_t*)&bres[m]       = *(const long2_t*)(rp + m * 64);
            *((long2_t*)&bres[m] + 1) = *(const long2_t*)(rp + m * 64 + 16);
        }
    }

    float s0r = 0.f, s1r = 0.f;
    float b0 = NEG_BIG, b1 = NEG_BIG, b2 = NEG_BIG, b3 = NEG_BIG, b4 = NEG_BIG;
    f32x16 svp;
#pragma unroll
    for (int r = 0; r < 16; ++r) svp[r] = NEG_BIG;

    __syncthreads();

// deferred epilogue: INS5 + EXPV on previous tile's masked values
#define EPI5() {                                                                \
        _Pragma("unroll")                                                       \
        for (int r = 0; r < 16; ++r) {                                          \
            float v = svp[r];                                                   \
            INS5(b0, b1, b2, b3, b4, v);                                        \
            if (r & 1) s1r += EXPV(v); else s0r += EXPV(v);                     \
        }                                                                       \
    }

#define TILE_BODY(JT, CUR) {                                                    \
        if ((JT) + 1 < NTILE) {                                                 \
            const int jb_ = j0c + ((JT) + 1) * 32;                              \
            char* bufn_ = lds + ((CUR) ^ BUFSZ);                                \
            _Pragma("unroll")                                                   \
            for (int u = 0; u < 8; ++u) {                                       \
                int jr = w * 8 + u;                                             \
                const uint8_t* src = zn8 + (size_t)(jb_ + jr) * D_DIM           \
                                     + ((l ^ (jr & 7)) << 4);                   \
                char* dst = bufn_ + jr * 1024;                                  \
                __builtin_amdgcn_global_load_lds(                               \
                    (const __attribute__((address_space(1))) uint32_t*)src,     \
                    (__attribute__((address_space(3))) uint32_t*)dst, 16, 0, 0);\
            }                                                                   \
        }                                                                       \
        f32x16 acc0, acc1;                                                      \
        _Pragma("unroll")                                                       \
        for (int r = 0; r < 16; ++r) { acc0[r] = 0.f; acc1[r] = 0.f; }          \
        __builtin_amdgcn_s_setprio(1);                                          \
        _Pragma("unroll")                                                       \
        for (int m = 0; m < 16; ++m) {                                          \
            asm volatile("" : "+a"(bres[m]));  /* resident in AGPR half */      \
            const char* pl_ = (m & 1) ? a10 : a00;                              \
            const char* ph_ = (m & 1) ? a11 : a01;                              \
            i32x8 a;                                                            \
            *(long2_t*)&a       = *(const long2_t*)(pl_ + (CUR) + (m >> 1) * 128);\
            *((long2_t*)&a + 1) = *(const long2_t*)(ph_ + (CUR) + (m >> 1) * 128);\
            if (m & 1)                                                          \
                acc1 = __builtin_amdgcn_mfma_scale_f32_32x32x64_f8f6f4(         \
                    a, bres[m], acc1, 0, 0, 0, 127, 0, 127);                    \
            else                                                                \
                acc0 = __builtin_amdgcn_mfma_scale_f32_32x32x64_f8f6f4(         \
                    a, bres[m], acc0, 0, 0, 0, 127, 0, 127);                    \
        }                                                                       \
        __builtin_amdgcn_s_setprio(0);                                          \
        EPI5();   /* previous tile's heavy epilogue, overlaps this phase */     \
        if ((JT) != diag_jt) {                                                  \
            _Pragma("unroll")                                                   \
            for (int r = 0; r < 16; ++r) svp[r] = acc0[r] + acc1[r];            \
        } else {                                                                \
            const int dd2 = i_lane - (j0c + (JT) * 32) - 4 * h;                 \
            _Pragma("unroll")                                                   \
            for (int r = 0; r < 16; ++r) {                                      \
                const int jm = (r & 3) + 8 * (r >> 2);                          \
                float v = acc0[r] + acc1[r];                                    \
                svp[r] = (dd2 == jm) ? NEG_BIG : v;                             \
            }                                                                   \
        }                                                                       \
        __syncthreads();                                                        \
    }

    for (int jt = 0; jt < NTILE; jt += 2) {
        TILE_BODY(jt, 0);
        TILE_BODY(jt + 1, BUFSZ);
    }
    EPI5();   // flush last tile's deferred epilogue
#undef TILE_BODY
#undef EPI5

    float s_run = s0r + s1r;
    // merge the two h-halves: lanes l and l^32 hold complementary j-rows of col i
    s_run += __shfl_xor(s_run, 32);
    {
        float o0 = __shfl_xor(b0, 32), o1 = __shfl_xor(b1, 32), o2 = __shfl_xor(b2, 32),
              o3 = __shfl_xor(b3, 32), o4 = __shfl_xor(b4, 32);
        INS5(b0, b1, b2, b3, b4, o0); INS5(b0, b1, b2, b3, b4, o1);
        INS5(b0, b1, b2, b3, b4, o2); INS5(b0, b1, b2, b3, b4, o3);
        INS5(b0, b1, b2, b3, b4, o4);
    }
    if (h == 0) {
        float* p = pstats + ((size_t)ch * N_ROWS + i_lane) * 8;
        p[0] = s_run; p[1] = b0; p[2] = b1; p[3] = b2; p[4] = b3; p[5] = b4;
        p[6] = 0.f; p[7] = 0.f;
    }
}

// ---------------- K3: per-row merge of 8 chunk partials ----------------
__global__ __launch_bounds__(128) void reduce1(const float* __restrict__ pstats,
                                               float* __restrict__ partial) {
    int row = blockIdx.x * 128 + threadIdx.x;
    float S = 0.f;
    float b0 = NEG_BIG, b1 = NEG_BIG, b2 = NEG_BIG, b3 = NEG_BIG, b4 = NEG_BIG;
#pragma unroll
    for (int c = 0; c < NCHUNK; ++c) {
        const float* p = pstats + ((size_t)c * N_ROWS + row) * 8;
        S += p[0];
        float v0 = p[1], v1 = p[2], v2 = p[3], v3 = p[4], v4 = p[5];
        INS5(b0, b1, b2, b3, b4, v0); INS5(b0, b1, b2, b3, b4, v1);
        INS5(b0, b1, b2, b3, b4, v2); INS5(b0, b1, b2, b3, b4, v3);
        INS5(b0, b1, b2, b3, b4, v4);
    }
    float S5 = EXPV(b0) + EXPV(b1) + EXPV(b2) + EXPV(b3) + EXPV(b4);
    float loss = __logf(S) - __logf(S5);
#pragma unroll
    for (int m = 1; m < 64; m <<= 1) loss += __shfl_xor(loss, m);
    __shared__ float rr[2];
    if ((threadIdx.x & 63) == 0) rr[threadIdx.x >> 6] = loss;
    __syncthreads();
    if (threadIdx.x == 0) partial[blockIdx.x] = rr[0] + rr[1];
}

// ---------------- K4: final mean ----------------
__global__ void reduce2(const float* __restrict__ partial, float* __restrict__ out) {
    float v = partial[threadIdx.x];   // 64 partials
#pragma unroll
    for (int m = 1; m < 64; m <<= 1) v += __shfl_xor(v, m);
    if (threadIdx.x == 0) out[0] = v * (1.0f / N_ROWS);
}

extern "C" void kernel_launch(void* const* d_in, const int* in_sizes, int n_in,
                              void* d_out, int out_size, void* d_ws, size_t ws_size,
                              hipStream_t stream) {
    const float* z = (const float*)d_in[0];
    float* out = (float*)d_out;
    uint8_t* zn8   = (uint8_t*)d_ws;                                   // 8 MB
    float* pstats  = (float*)((char*)d_ws + (size_t)8 * 1024 * 1024);  // 2 MB
    float* partial = (float*)((char*)d_ws + (size_t)10 * 1024 * 1024); // 256 B

    norm_kernel<<<N_ROWS / 4, 256, 0, stream>>>(z, zn8);
    sim_kernel<<<64 * NCHUNK, 256, 0, stream>>>(zn8, pstats);
    reduce1<<<N_ROWS / 128, 128, 0, stream>>>(pstats, partial);
    reduce2<<<1, 64, 0, stream>>>(partial, out);
}

// Round 10
// 142.169 us; speedup vs baseline: 1.1478x; 1.1478x over previous
//
#include <hip/hip_runtime.h>
#include <stdint.h>

#define N_ROWS 8192
#define D_DIM  1024
#define NEG_BIG -1e30f
#define NCHUNK 8
#define CHUNK_J 1024
#define NTILE 32            // 32 j-cols per tile, 32 tiles per chunk
#define BUFSZ (32 * 1024)   // 32 rows x 1024 B, swizzled (16B-slot XOR) layout

typedef __attribute__((ext_vector_type(16))) float f32x16;
typedef __attribute__((ext_vector_type(8)))  int   i32x8;
typedef __attribute__((ext_vector_type(2)))  long  long2_t;

// log2(e) * 10 : exp(10v - 10) = exp2(v*C - C)
#define EXPC 14.4269504089f
#define EXPV(v) exp2f(fmaf((v), EXPC, -EXPC))

// branchless sorted insert of v into descending 5-list, med3 form (5 ops)
#define INS5(b0,b1,b2,b3,b4,v) {                        \
    float _n4 = __builtin_amdgcn_fmed3f(b3, (v), b4);   \
    float _n3 = __builtin_amdgcn_fmed3f(b2, (v), b3);   \
    float _n2 = __builtin_amdgcn_fmed3f(b1, (v), b2);   \
    float _n1 = __builtin_amdgcn_fmed3f(b0, (v), b1);   \
    b0 = fmaxf(b0, (v)); b1 = _n1; b2 = _n2; b3 = _n3; b4 = _n4; }

// f32 -> OCP e4m3fn, RNE, with denormals. |x| <= ~1 here (normalized rows).
static __device__ inline uint32_t f2e4m3(float x) {
    uint32_t u = __float_as_uint(x);
    uint32_t s = (u >> 24) & 0x80u;
    uint32_t a = u & 0x7fffffffu;
    uint32_t e = a >> 23;
    uint32_t out;
    if (e >= 121u) {
        uint32_t mant = a & 0x7fffffu;
        uint32_t comb = ((e - 120u) << 3) | (mant >> 20);
        uint32_t rem  = mant & 0xfffffu;
        comb += (rem > 0x80000u) || ((rem == 0x80000u) && (comb & 1u));
        out = comb;
    } else {
        float scl = __uint_as_float(a) * 512.0f;
        out = (uint32_t)(int)rintf(scl);
    }
    return s | out;
}

// ---------------- K1: row-normalize f32 -> fp8 e4m3 ----------------
__global__ __launch_bounds__(256) void norm_kernel(const float* __restrict__ z,
                                                   uint8_t* __restrict__ zn8) {
    int wave = threadIdx.x >> 6;
    int lane = threadIdx.x & 63;
    int row  = blockIdx.x * 4 + wave;
    const float* zr = z + (size_t)row * D_DIM;
    float4 c[4];
    float ss = 0.f;
#pragma unroll
    for (int i = 0; i < 4; ++i) {
        c[i] = *(const float4*)(zr + i * 256 + lane * 4);
        ss += c[i].x*c[i].x + c[i].y*c[i].y + c[i].z*c[i].z + c[i].w*c[i].w;
    }
#pragma unroll
    for (int m = 1; m < 64; m <<= 1) ss += __shfl_xor(ss, m);
    float scale = 1.0f / fmaxf(sqrtf(ss), 1e-12f);
    uint8_t* zo = zn8 + (size_t)row * D_DIM;
#pragma unroll
    for (int i = 0; i < 4; ++i) {
        uint32_t d = f2e4m3(c[i].x * scale)
                   | (f2e4m3(c[i].y * scale) << 8)
                   | (f2e4m3(c[i].z * scale) << 16)
                   | (f2e4m3(c[i].w * scale) << 24);
        *(uint32_t*)(zo + i * 256 + lane * 4) = d;
    }
}

// ---------------- K2: fused fp8 sim via scale-MFMA K=64, 2 resident sets ----
// grid: 32 i-blocks (256 rows) x 8 j-chunks. 1 block/CU, 1 wave/SIMD,
// ~512-reg budget: TWO resident i-col sets (bres: rows i0w.., cres: +128)
// = 256 pinned VGPRs; each staged A-fragment feeds 2 MFMAs (4 acc chains).
// Per-CU LDS-read traffic halves vs the 128-row layout; MFMA total unchanged.
// LDS swizzle: 16B-slot s of row jr holds global slot s^(jr&7); reads via
// 4 per-lane base pointers + immediate offsets (conflict-free).
__global__ __launch_bounds__(256, 1) void sim_kernel(const uint8_t* __restrict__ zn8,
                                                     float* __restrict__ pstats) {
    __shared__ __align__(16) char lds[2 * BUFSZ];
    const int tid  = threadIdx.x;
    const int w    = tid >> 6;
    const int l    = tid & 63;
    const int r32  = l & 31;
    const int h    = l >> 5;
    const int f3   = r32 & 7;
    const int ib   = blockIdx.x >> 3;
    const int ch   = blockIdx.x & 7;
    const int i0w  = ib * 256 + w * 32;          // set0 rows; set1 = +128
    const int j0c  = ch * CHUNK_J;
    const int i_lane  = i0w + r32;
    const int i_lane2 = i_lane + 128;
    const int d0 = ib * 8 + w;                   // i0w >> 5
    const int d1 = d0 + 4;                       // (i0w+128) >> 5
    const int diag_jt0 = ((d0 >> 5) == ch) ? (d0 & 31) : -1;
    const int diag_jt1 = ((d1 >> 5) == ch) ? (d1 & 31) : -1;

    // 4 per-lane LDS read base pointers
    const int b0f = f3 & 1, b1f = (f3 >> 1) & 1, b2f = f3 >> 2;
    const int e0 = r32 * 1024 + (b2f << 6) + ((h ^ b1f) << 5) + (b0f << 4);
    const char* a00 = lds + e0;          // even m, low 16B
    const char* a01 = lds + (e0 ^ 16);   // even m, high 16B
    const char* a10 = lds + (e0 ^ 64);   // odd m, low 16B
    const char* a11 = lds + (e0 ^ 80);   // odd m, high 16B

    // prologue: stage tile 0 into buffer 0
#pragma unroll
    for (int u = 0; u < 8; ++u) {
        int jr = w * 8 + u;
        const uint8_t* src = zn8 + (size_t)(j0c + jr) * D_DIM + ((l ^ (jr & 7)) << 4);
        char* dst = lds + jr * 1024;
        __builtin_amdgcn_global_load_lds(
            (const __attribute__((address_space(1))) uint32_t*)src,
            (__attribute__((address_space(3))) uint32_t*)dst, 16, 0, 0);
    }

    // resident B-operands: set0 col i_lane, set1 col i_lane2
    i32x8 bres[16], cres[16];
    {
        const uint8_t* rp  = zn8 + (size_t)i_lane  * D_DIM + h * 32;
        const uint8_t* rp2 = zn8 + (size_t)i_lane2 * D_DIM + h * 32;
#pragma unroll
        for (int m = 0; m < 16; ++m) {
            *(long2_t*)&bres[m]       = *(const long2_t*)(rp + m * 64);
            *((long2_t*)&bres[m] + 1) = *(const long2_t*)(rp + m * 64 + 16);
            *(long2_t*)&cres[m]       = *(const long2_t*)(rp2 + m * 64);
            *((long2_t*)&cres[m] + 1) = *(const long2_t*)(rp2 + m * 64 + 16);
        }
    }

    float s0r = 0.f, s1r = 0.f, s2r = 0.f, s3r = 0.f;
    float b0 = NEG_BIG, b1 = NEG_BIG, b2 = NEG_BIG, b3 = NEG_BIG, b4 = NEG_BIG;
    float c0 = NEG_BIG, c1 = NEG_BIG, c2 = NEG_BIG, c3 = NEG_BIG, c4 = NEG_BIG;

    __syncthreads();

#define TILE_BODY(JT, CUR) {                                                    \
        if ((JT) + 1 < NTILE) {                                                 \
            const int jb_ = j0c + ((JT) + 1) * 32;                              \
            char* bufn_ = lds + ((CUR) ^ BUFSZ);                                \
            _Pragma("unroll")                                                   \
            for (int u = 0; u < 8; ++u) {                                       \
                int jr = w * 8 + u;                                             \
                const uint8_t* src = zn8 + (size_t)(jb_ + jr) * D_DIM           \
                                     + ((l ^ (jr & 7)) << 4);                   \
                char* dst = bufn_ + jr * 1024;                                  \
                __builtin_amdgcn_global_load_lds(                               \
                    (const __attribute__((address_space(1))) uint32_t*)src,     \
                    (__attribute__((address_space(3))) uint32_t*)dst, 16, 0, 0);\
            }                                                                   \
        }                                                                       \
        f32x16 acc0, acc1, acc2, acc3;                                          \
        _Pragma("unroll")                                                       \
        for (int r = 0; r < 16; ++r) {                                          \
            acc0[r] = 0.f; acc1[r] = 0.f; acc2[r] = 0.f; acc3[r] = 0.f;         \
        }                                                                       \
        __builtin_amdgcn_s_setprio(1);                                          \
        _Pragma("unroll")                                                       \
        for (int m = 0; m < 16; ++m) {                                          \
            asm volatile("" : "+v"(bres[m]), "+v"(cres[m]));                    \
            const char* pl_ = (m & 1) ? a10 : a00;                              \
            const char* ph_ = (m & 1) ? a11 : a01;                              \
            i32x8 a;                                                            \
            *(long2_t*)&a       = *(const long2_t*)(pl_ + (CUR) + (m >> 1) * 128);\
            *((long2_t*)&a + 1) = *(const long2_t*)(ph_ + (CUR) + (m >> 1) * 128);\
            if (m & 1) {                                                        \
                acc1 = __builtin_amdgcn_mfma_scale_f32_32x32x64_f8f6f4(         \
                    a, bres[m], acc1, 0, 0, 0, 127, 0, 127);                    \
                acc3 = __builtin_amdgcn_mfma_scale_f32_32x32x64_f8f6f4(         \
                    a, cres[m], acc3, 0, 0, 0, 127, 0, 127);                    \
            } else {                                                            \
                acc0 = __builtin_amdgcn_mfma_scale_f32_32x32x64_f8f6f4(         \
                    a, bres[m], acc0, 0, 0, 0, 127, 0, 127);                    \
                acc2 = __builtin_amdgcn_mfma_scale_f32_32x32x64_f8f6f4(         \
                    a, cres[m], acc2, 0, 0, 0, 127, 0, 127);                    \
            }                                                                   \
        }                                                                       \
        __builtin_amdgcn_s_setprio(0);                                          \
        /* set0 epilogue */                                                     \
        if ((JT) != diag_jt0) {                                                 \
            _Pragma("unroll")                                                   \
            for (int r = 0; r < 16; ++r) {                                      \
                float v = acc0[r] + acc1[r];                                    \
                INS5(b0, b1, b2, b3, b4, v);                                    \
                if (r & 1) s1r += EXPV(v); else s0r += EXPV(v);                 \
            }                                                                   \
        } else {                                                                \
            const int dd2 = i_lane - (j0c + (JT) * 32) - 4 * h;                 \
            _Pragma("unroll")                                                   \
            for (int r = 0; r < 16; ++r) {                                      \
                const int jm = (r & 3) + 8 * (r >> 2);                          \
                float v = acc0[r] + acc1[r];                                    \
                if (dd2 == jm) v = NEG_BIG;                                     \
                INS5(b0, b1, b2, b3, b4, v);                                    \
                if (r & 1) s1r += EXPV(v); else s0r += EXPV(v);                 \
            }                                                                   \
        }                                                                       \
        /* set1 epilogue */                                                     \
        if ((JT) != diag_jt1) {                                                 \
            _Pragma("unroll")                                                   \
            for (int r = 0; r < 16; ++r) {                                      \
                float v = acc2[r] + acc3[r];                                    \
                INS5(c0, c1, c2, c3, c4, v);                                    \
                if (r & 1) s3r += EXPV(v); else s2r += EXPV(v);                 \
            }                                                                   \
        } else {                                                                \
            const int dd2 = i_lane2 - (j0c + (JT) * 32) - 4 * h;                \
            _Pragma("unroll")                                                   \
            for (int r = 0; r < 16; ++r) {                                      \
                const int jm = (r & 3) + 8 * (r >> 2);                          \
                float v = acc2[r] + acc3[r];                                    \
                if (dd2 == jm) v = NEG_BIG;                                     \
                INS5(c0, c1, c2, c3, c4, v);                                    \
                if (r & 1) s3r += EXPV(v); else s2r += EXPV(v);                 \
            }                                                                   \
        }                                                                       \
        __syncthreads();                                                        \
    }

    for (int jt = 0; jt < NTILE; jt += 2) {
        TILE_BODY(jt, 0);
        TILE_BODY(jt + 1, BUFSZ);
    }
#undef TILE_BODY

    // merge h-halves (lanes l, l^32 hold complementary j-rows of same i-col)
    float sr0 = s0r + s1r;  sr0 += __shfl_xor(sr0, 32);
    float sr1 = s2r + s3r;  sr1 += __shfl_xor(sr1, 32);
    {
        float o0 = __shfl_xor(b0, 32), o1 = __shfl_xor(b1, 32), o2 = __shfl_xor(b2, 32),
              o3 = __shfl_xor(b3, 32), o4 = __shfl_xor(b4, 32);
        INS5(b0, b1, b2, b3, b4, o0); INS5(b0, b1, b2, b3, b4, o1);
        INS5(b0, b1, b2, b3, b4, o2); INS5(b0, b1, b2, b3, b4, o3);
        INS5(b0, b1, b2, b3, b4, o4);
    }
    {
        float o0 = __shfl_xor(c0, 32), o1 = __shfl_xor(c1, 32), o2 = __shfl_xor(c2, 32),
              o3 = __shfl_xor(c3, 32), o4 = __shfl_xor(c4, 32);
        INS5(c0, c1, c2, c3, c4, o0); INS5(c0, c1, c2, c3, c4, o1);
        INS5(c0, c1, c2, c3, c4, o2); INS5(c0, c1, c2, c3, c4, o3);
        INS5(c0, c1, c2, c3, c4, o4);
    }
    if (h == 0) {
        float* p = pstats + ((size_t)ch * N_ROWS + i_lane) * 8;
        p[0] = sr0; p[1] = b0; p[2] = b1; p[3] = b2; p[4] = b3; p[5] = b4;
        p[6] = 0.f; p[7] = 0.f;
        float* q = pstats + ((size_t)ch * N_ROWS + i_lane2) * 8;
        q[0] = sr1; q[1] = c0; q[2] = c1; q[3] = c2; q[4] = c3; q[5] = c4;
        q[6] = 0.f; q[7] = 0.f;
    }
}

// ---------------- K3: per-row merge of 8 chunk partials ----------------
__global__ __launch_bounds__(128) void reduce1(const float* __restrict__ pstats,
                                               float* __restrict__ partial) {
    int row = blockIdx.x * 128 + threadIdx.x;
    float S = 0.f;
    float b0 = NEG_BIG, b1 = NEG_BIG, b2 = NEG_BIG, b3 = NEG_BIG, b4 = NEG_BIG;
#pragma unroll
    for (int c = 0; c < NCHUNK; ++c) {
        const float* p = pstats + ((size_t)c * N_ROWS + row) * 8;
        S += p[0];
        float v0 = p[1], v1 = p[2], v2 = p[3], v3 = p[4], v4 = p[5];
        INS5(b0, b1, b2, b3, b4, v0); INS5(b0, b1, b2, b3, b4, v1);
        INS5(b0, b1, b2, b3, b4, v2); INS5(b0, b1, b2, b3, b4, v3);
        INS5(b0, b1, b2, b3, b4, v4);
    }
    float S5 = EXPV(b0) + EXPV(b1) + EXPV(b2) + EXPV(b3) + EXPV(b4);
    float loss = __logf(S) - __logf(S5);
#pragma unroll
    for (int m = 1; m < 64; m <<= 1) loss += __shfl_xor(loss, m);
    __shared__ float rr[2];
    if ((threadIdx.x & 63) == 0) rr[threadIdx.x >> 6] = loss;
    __syncthreads();
    if (threadIdx.x == 0) partial[blockIdx.x] = rr[0] + rr[1];
}

// ---------------- K4: final mean ----------------
__global__ void reduce2(const float* __restrict__ partial, float* __restrict__ out) {
    float v = partial[threadIdx.x];   // 64 partials
#pragma unroll
    for (int m = 1; m < 64; m <<= 1) v += __shfl_xor(v, m);
    if (threadIdx.x == 0) out[0] = v * (1.0f / N_ROWS);
}

extern "C" void kernel_launch(void* const* d_in, const int* in_sizes, int n_in,
                              void* d_out, int out_size, void* d_ws, size_t ws_size,
                              hipStream_t stream) {
    const float* z = (const float*)d_in[0];
    float* out = (float*)d_out;
    uint8_t* zn8   = (uint8_t*)d_ws;                                   // 8 MB
    float* pstats  = (float*)((char*)d_ws + (size_t)8 * 1024 * 1024);  // 2 MB
    float* partial = (float*)((char*)d_ws + (size_t)10 * 1024 * 1024); // 256 B

    norm_kernel<<<N_ROWS / 4, 256, 0, stream>>>(z, zn8);
    sim_kernel<<<32 * NCHUNK, 256, 0, stream>>>(zn8, pstats);
    reduce1<<<N_ROWS / 128, 128, 0, stream>>>(pstats, partial);
    reduce2<<<1, 64, 0, stream>>>(partial, out);
}

// Round 11
// 94.017 us; speedup vs baseline: 1.7357x; 1.5122x over previous
//
#include <hip/hip_runtime.h>
#include <stdint.h>

#define N_ROWS 8192
#define D_DIM  1024
#define NEG_BIG -1e30f
#define NCHUNK 8
#define CHUNK_J 1024
#define NTILE 32            // 32 j-cols per tile, 32 tiles per chunk
#define BUFSZ (32 * 1024)   // 32 rows x 1024 B, swizzled (16B-slot XOR) layout

typedef __attribute__((ext_vector_type(16))) float f32x16;
typedef __attribute__((ext_vector_type(8)))  int   i32x8;
typedef __attribute__((ext_vector_type(2)))  long  long2_t;

// log2(e) * 10 : exp(10v - 10) = exp2(v*C - C)
#define EXPC 14.4269504089f
#define EXPV(v) exp2f(fmaf((v), EXPC, -EXPC))

// branchless sorted insert of v into descending 5-list, med3 form (5 ops)
#define INS5(b0,b1,b2,b3,b4,v) {                        \
    float _n4 = __builtin_amdgcn_fmed3f(b3, (v), b4);   \
    float _n3 = __builtin_amdgcn_fmed3f(b2, (v), b3);   \
    float _n2 = __builtin_amdgcn_fmed3f(b1, (v), b2);   \
    float _n1 = __builtin_amdgcn_fmed3f(b0, (v), b1);   \
    b0 = fmaxf(b0, (v)); b1 = _n1; b2 = _n2; b3 = _n3; b4 = _n4; }

// f32 -> OCP e4m3fn, RNE, with denormals. |x| <= ~1 here (normalized rows).
static __device__ inline uint32_t f2e4m3(float x) {
    uint32_t u = __float_as_uint(x);
    uint32_t s = (u >> 24) & 0x80u;
    uint32_t a = u & 0x7fffffffu;
    uint32_t e = a >> 23;
    uint32_t out;
    if (e >= 121u) {
        uint32_t mant = a & 0x7fffffu;
        uint32_t comb = ((e - 120u) << 3) | (mant >> 20);
        uint32_t rem  = mant & 0xfffffu;
        comb += (rem > 0x80000u) || ((rem == 0x80000u) && (comb & 1u));
        out = comb;
    } else {
        float scl = __uint_as_float(a) * 512.0f;
        out = (uint32_t)(int)rintf(scl);
    }
    return s | out;
}

// ---------------- K1: row-normalize f32 -> fp8 e4m3 ----------------
__global__ __launch_bounds__(256) void norm_kernel(const float* __restrict__ z,
                                                   uint8_t* __restrict__ zn8) {
    int wave = threadIdx.x >> 6;
    int lane = threadIdx.x & 63;
    int row  = blockIdx.x * 4 + wave;
    const float* zr = z + (size_t)row * D_DIM;
    float4 c[4];
    float ss = 0.f;
#pragma unroll
    for (int i = 0; i < 4; ++i) {
        c[i] = *(const float4*)(zr + i * 256 + lane * 4);
        ss += c[i].x*c[i].x + c[i].y*c[i].y + c[i].z*c[i].z + c[i].w*c[i].w;
    }
#pragma unroll
    for (int m = 1; m < 64; m <<= 1) ss += __shfl_xor(ss, m);
    float scale = 1.0f / fmaxf(sqrtf(ss), 1e-12f);
    uint8_t* zo = zn8 + (size_t)row * D_DIM;
#pragma unroll
    for (int i = 0; i < 4; ++i) {
        uint32_t d = f2e4m3(c[i].x * scale)
                   | (f2e4m3(c[i].y * scale) << 8)
                   | (f2e4m3(c[i].z * scale) << 16)
                   | (f2e4m3(c[i].w * scale) << 24);
        *(uint32_t*)(zo + i * 256 + lane * 4) = d;
    }
}

// ---------------- K2: fused fp8 sim via scale-MFMA K=64 ----------------
// grid: 64 i-blocks (128 rows, 32/wave) x 8 j-chunks (1024 cols).
// Swapped MFMA: A = streamed j-tile (LDS), B = resident i-rows.
// LDS swizzle: 16B-slot s of row jr holds global slot s^(jr&7) (full 3-bit
// involution). Read: 4 per-lane base pointers + immediate offsets.
// ANTI-LOCKSTEP: the 2 co-resident blocks/CU run identical period lengths and
// launch together -> phase lockstep (both burst LDS, then both burst VALU;
// measured round 6: pipes sum to 100% of period, zero overlap). Randomized
// entry stagger (0..~6000 cyc) decorrelates their barrier rhythms so one
// block's ds_read phase overlaps the other's MFMA+VALU phase.
__global__ __launch_bounds__(256, 2) void sim_kernel(const uint8_t* __restrict__ zn8,
                                                     float* __restrict__ pstats) {
    __shared__ __align__(16) char lds[2 * BUFSZ];
    const int tid  = threadIdx.x;
    const int w    = tid >> 6;
    const int l    = tid & 63;
    const int r32  = l & 31;
    const int h    = l >> 5;
    const int f3   = r32 & 7;
    const int ib   = blockIdx.x >> 3;
    const int ch   = blockIdx.x & 7;
    const int i0w  = ib * 128 + w * 32;
    const int j0c  = ch * CHUNK_J;
    const int i_lane = i0w + r32;
    const int diag_jt = (ch == (ib >> 3)) ? ((ib & 7) * 4 + w) : -1;

    // phase-stagger: wave-uniform random delay per block (anti-lockstep)
    {
        unsigned dly = (blockIdx.x * 2654435761u) >> 27;   // 0..31
        for (unsigned t = 0; t < dly; ++t) __builtin_amdgcn_s_sleep(3); // ~192 cyc
    }

    // 4 per-lane LDS read base pointers
    const int b0f = f3 & 1, b1f = (f3 >> 1) & 1, b2f = f3 >> 2;
    const int e0 = r32 * 1024 + (b2f << 6) + ((h ^ b1f) << 5) + (b0f << 4);
    const char* a00 = lds + e0;          // even m, low 16B
    const char* a01 = lds + (e0 ^ 16);   // even m, high 16B
    const char* a10 = lds + (e0 ^ 64);   // odd m, low 16B
    const char* a11 = lds + (e0 ^ 80);   // odd m, high 16B

    // prologue: stage tile 0 into buffer 0
#pragma unroll
    for (int u = 0; u < 8; ++u) {
        int jr = w * 8 + u;
        const uint8_t* src = zn8 + (size_t)(j0c + jr) * D_DIM + ((l ^ (jr & 7)) << 4);
        char* dst = lds + jr * 1024;
        __builtin_amdgcn_global_load_lds(
            (const __attribute__((address_space(1))) uint32_t*)src,
            (__attribute__((address_space(3))) uint32_t*)dst, 16, 0, 0);
    }

    // resident B-operand: lane holds col i_lane; bres[m] = k bytes [m*64+h*32, +32)
    i32x8 bres[16];
    {
        const uint8_t* rp = zn8 + (size_t)i_lane * D_DIM + h * 32;
#pragma unroll
        for (int m = 0; m < 16; ++m) {
            *(long2_t*)&bres[m]       = *(const long2_t*)(rp + m * 64);
            *((long2_t*)&bres[m] + 1) = *(const long2_t*)(rp + m * 64 + 16);
        }
    }

    float s0r = 0.f, s1r = 0.f;
    float b0 = NEG_BIG, b1 = NEG_BIG, b2 = NEG_BIG, b3 = NEG_BIG, b4 = NEG_BIG;

    __syncthreads();

#define TILE_BODY(JT, CUR) {                                                    \
        if ((JT) + 1 < NTILE) {                                                 \
            const int jb_ = j0c + ((JT) + 1) * 32;                              \
            char* bufn_ = lds + ((CUR) ^ BUFSZ);                                \
            _Pragma("unroll")                                                   \
            for (int u = 0; u < 8; ++u) {                                       \
                int jr = w * 8 + u;                                             \
                const uint8_t* src = zn8 + (size_t)(jb_ + jr) * D_DIM           \
                                     + ((l ^ (jr & 7)) << 4);                   \
                char* dst = bufn_ + jr * 1024;                                  \
                __builtin_amdgcn_global_load_lds(                               \
                    (const __attribute__((address_space(1))) uint32_t*)src,     \
                    (__attribute__((address_space(3))) uint32_t*)dst, 16, 0, 0);\
            }                                                                   \
        }                                                                       \
        f32x16 acc0, acc1;                                                      \
        _Pragma("unroll")                                                       \
        for (int r = 0; r < 16; ++r) { acc0[r] = 0.f; acc1[r] = 0.f; }          \
        __builtin_amdgcn_s_setprio(1);                                          \
        _Pragma("unroll")                                                       \
        for (int m = 0; m < 16; ++m) {                                          \
            asm volatile("" : "+v"(bres[m]));  /* keep resident */              \
            const char* pl_ = (m & 1) ? a10 : a00;                              \
            const char* ph_ = (m & 1) ? a11 : a01;                              \
            i32x8 a;                                                            \
            *(long2_t*)&a       = *(const long2_t*)(pl_ + (CUR) + (m >> 1) * 128);\
            *((long2_t*)&a + 1) = *(const long2_t*)(ph_ + (CUR) + (m >> 1) * 128);\
            if (m & 1)                                                          \
                acc1 = __builtin_amdgcn_mfma_scale_f32_32x32x64_f8f6f4(         \
                    a, bres[m], acc1, 0, 0, 0, 127, 0, 127);                    \
            else                                                                \
                acc0 = __builtin_amdgcn_mfma_scale_f32_32x32x64_f8f6f4(         \
                    a, bres[m], acc0, 0, 0, 0, 127, 0, 127);                    \
        }                                                                       \
        __builtin_amdgcn_s_setprio(0);                                          \
        if ((JT) != diag_jt) {                                                  \
            _Pragma("unroll")                                                   \
            for (int r = 0; r < 16; ++r) {                                      \
                float v = acc0[r] + acc1[r];                                    \
                INS5(b0, b1, b2, b3, b4, v);                                    \
                if (r & 1) s1r += EXPV(v); else s0r += EXPV(v);                 \
            }                                                                   \
        } else {                                                                \
            const int dd2 = i_lane - (j0c + (JT) * 32) - 4 * h;                 \
            _Pragma("unroll")                                                   \
            for (int r = 0; r < 16; ++r) {                                      \
                const int jm = (r & 3) + 8 * (r >> 2);                          \
                float v = acc0[r] + acc1[r];                                    \
                if (dd2 == jm) v = NEG_BIG;                                     \
                INS5(b0, b1, b2, b3, b4, v);                                    \
                if (r & 1) s1r += EXPV(v); else s0r += EXPV(v);                 \
            }                                                                   \
        }                                                                       \
        __syncthreads();                                                        \
    }

    for (int jt = 0; jt < NTILE; jt += 2) {
        TILE_BODY(jt, 0);
        TILE_BODY(jt + 1, BUFSZ);
    }
#undef TILE_BODY

    float s_run = s0r + s1r;
    // merge the two h-halves: lanes l and l^32 hold complementary j-rows of col i
    s_run += __shfl_xor(s_run, 32);
    {
        float o0 = __shfl_xor(b0, 32), o1 = __shfl_xor(b1, 32), o2 = __shfl_xor(b2, 32),
              o3 = __shfl_xor(b3, 32), o4 = __shfl_xor(b4, 32);
        INS5(b0, b1, b2, b3, b4, o0); INS5(b0, b1, b2, b3, b4, o1);
        INS5(b0, b1, b2, b3, b4, o2); INS5(b0, b1, b2, b3, b4, o3);
        INS5(b0, b1, b2, b3, b4, o4);
    }
    if (h == 0) {
        float* p = pstats + ((size_t)ch * N_ROWS + i_lane) * 8;
        p[0] = s_run; p[1] = b0; p[2] = b1; p[3] = b2; p[4] = b3; p[5] = b4;
        p[6] = 0.f; p[7] = 0.f;
    }
}

// ---------------- K3: per-row merge of 8 chunk partials ----------------
__global__ __launch_bounds__(128) void reduce1(const float* __restrict__ pstats,
                                               float* __restrict__ partial) {
    int row = blockIdx.x * 128 + threadIdx.x;
    float S = 0.f;
    float b0 = NEG_BIG, b1 = NEG_BIG, b2 = NEG_BIG, b3 = NEG_BIG, b4 = NEG_BIG;
#pragma unroll
    for (int c = 0; c < NCHUNK; ++c) {
        const float* p = pstats + ((size_t)c * N_ROWS + row) * 8;
        S += p[0];
        float v0 = p[1], v1 = p[2], v2 = p[3], v3 = p[4], v4 = p[5];
        INS5(b0, b1, b2, b3, b4, v0); INS5(b0, b1, b2, b3, b4, v1);
        INS5(b0, b1, b2, b3, b4, v2); INS5(b0, b1, b2, b3, b4, v3);
        INS5(b0, b1, b2, b3, b4, v4);
    }
    float S5 = EXPV(b0) + EXPV(b1) + EXPV(b2) + EXPV(b3) + EXPV(b4);
    float loss = __logf(S) - __logf(S5);
#pragma unroll
    for (int m = 1; m < 64; m <<= 1) loss += __shfl_xor(loss, m);
    __shared__ float rr[2];
    if ((threadIdx.x & 63) == 0) rr[threadIdx.x >> 6] = loss;
    __syncthreads();
    if (threadIdx.x == 0) partial[blockIdx.x] = rr[0] + rr[1];
}

// ---------------- K4: final mean ----------------
__global__ void reduce2(const float* __restrict__ partial, float* __restrict__ out) {
    float v = partial[threadIdx.x];   // 64 partials
#pragma unroll
    for (int m = 1; m < 64; m <<= 1) v += __shfl_xor(v, m);
    if (threadIdx.x == 0) out[0] = v * (1.0f / N_ROWS);
}

extern "C" void kernel_launch(void* const* d_in, const int* in_sizes, int n_in,
                              void* d_out, int out_size, void* d_ws, size_t ws_size,
                              hipStream_t stream) {
    const float* z = (const float*)d_in[0];
    float* out = (float*)d_out;
    uint8_t* zn8   = (uint8_t*)d_ws;                                   // 8 MB
    float* pstats  = (float*)((char*)d_ws + (size_t)8 * 1024 * 1024);  // 2 MB
    float* partial = (float*)((char*)d_ws + (size_t)10 * 1024 * 1024); // 256 B

    norm_kernel<<<N_ROWS / 4, 256, 0, stream>>>(z, zn8);
    sim_kernel<<<64 * NCHUNK, 256, 0, stream>>>(zn8, pstats);
    reduce1<<<N_ROWS / 128, 128, 0, stream>>>(pstats, partial);
    reduce2<<<1, 64, 0, stream>>>(partial, out);
}

// Round 12
// 89.350 us; speedup vs baseline: 1.8263x; 1.0522x over previous
//
#include <hip/hip_runtime.h>
#include <stdint.h>

#define N_ROWS 8192
#define D_DIM  1024
#define NEG_BIG -1e30f
#define NCHUNK 8
#define CHUNK_J 1024
#define NTILE 32              // 32 j-cols per tile, 32 tiles per chunk
#define NBLK_LDS 12           // m-blocks 0..11 staged in LDS; 12..15 direct L2
#define BUFSZ (NBLK_LDS * 2048)   // 24576 B per buffer

typedef __attribute__((ext_vector_type(16))) float f32x16;
typedef __attribute__((ext_vector_type(8)))  int   i32x8;
typedef __attribute__((ext_vector_type(2)))  long  long2_t;

// exp(10v - 10) = exp2(v*C - C), raw v_exp_f32 (1 instr vs ocml's ~4)
#define EXPC 14.4269504089f
#define EXPRAW(dst, v) { float _a = fmaf((v), EXPC, -EXPC);                 \
    asm("v_exp_f32 %0, %1" : "=v"(dst) : "v"(_a)); }

// branchless sorted insert of v into descending 5-list, med3 form (5 ops)
#define INS5(b0,b1,b2,b3,b4,v) {                        \
    float _n4 = __builtin_amdgcn_fmed3f(b3, (v), b4);   \
    float _n3 = __builtin_amdgcn_fmed3f(b2, (v), b3);   \
    float _n2 = __builtin_amdgcn_fmed3f(b1, (v), b2);   \
    float _n1 = __builtin_amdgcn_fmed3f(b0, (v), b1);   \
    b0 = fmaxf(b0, (v)); b1 = _n1; b2 = _n2; b3 = _n3; b4 = _n4; }

// f32 -> OCP e4m3fn, RNE, with denormals. |x| <= ~1 here (normalized rows).
static __device__ inline uint32_t f2e4m3(float x) {
    uint32_t u = __float_as_uint(x);
    uint32_t s = (u >> 24) & 0x80u;
    uint32_t a = u & 0x7fffffffu;
    uint32_t e = a >> 23;
    uint32_t out;
    if (e >= 121u) {
        uint32_t mant = a & 0x7fffffu;
        uint32_t comb = ((e - 120u) << 3) | (mant >> 20);
        uint32_t rem  = mant & 0xfffffu;
        comb += (rem > 0x80000u) || ((rem == 0x80000u) && (comb & 1u));
        out = comb;
    } else {
        float scl = __uint_as_float(a) * 512.0f;
        out = (uint32_t)(int)rintf(scl);
    }
    return s | out;
}

// ---------------- K1: row-normalize f32 -> fp8, FRAGMENT-BLOCKED layout ------
// Layout: block(J, m) = 2048 B at ((J*16 + m)*2048); holds rows J*32..+31,
// k-bytes m*64..+63. Fragment lane l' = (row&31) + 32*((k>>5)&1); its lo-16B
// (k&16==0) at l'*16, hi-16B at 1024 + l'*16, byte position k&15.
// This is EXACTLY the 32x32x64 A/B fragment each lane consumes -> staging is
// a linear copy and all operand loads are coalesced base + l*16.
__global__ __launch_bounds__(256) void norm_kernel(const float* __restrict__ z,
                                                   uint8_t* __restrict__ zn8b) {
    int wave = threadIdx.x >> 6;
    int lane = threadIdx.x & 63;
    int row  = blockIdx.x * 4 + wave;
    const float* zr = z + (size_t)row * D_DIM;
    float4 c[4];
    float ss = 0.f;
#pragma unroll
    for (int i = 0; i < 4; ++i) {
        c[i] = *(const float4*)(zr + i * 256 + lane * 4);
        ss += c[i].x*c[i].x + c[i].y*c[i].y + c[i].z*c[i].z + c[i].w*c[i].w;
    }
#pragma unroll
    for (int m = 1; m < 64; m <<= 1) ss += __shfl_xor(ss, m);
    float scale = 1.0f / fmaxf(sqrtf(ss), 1e-12f);
    const int J = row >> 5, j31 = row & 31;
    uint8_t* base = zn8b + (size_t)J * 16 * 2048;
#pragma unroll
    for (int i = 0; i < 4; ++i) {
        uint32_t d = f2e4m3(c[i].x * scale)
                   | (f2e4m3(c[i].y * scale) << 8)
                   | (f2e4m3(c[i].z * scale) << 16)
                   | (f2e4m3(c[i].w * scale) << 24);
        int k0 = i * 256 + lane * 4;
        int m  = k0 >> 6;
        int q  = (k0 >> 4) & 1;
        int lp = j31 + 32 * ((k0 >> 5) & 1);
        *(uint32_t*)(base + m * 2048 + q * 1024 + lp * 16 + (k0 & 15)) = d;
    }
}

// ---------------- K2: fused fp8 sim, split-source A-stream -------------------
// grid: 64 i-blocks (128 rows, 32/wave) x 8 j-chunks. Swapped MFMA:
// A = streamed j-tile, B = resident i-cols (128 VGPR). Per tile, 16 K=64
// scale-MFMAs: m 0..11 read A from LDS (linearly staged, conflict-floor reads
// at base+l*16), m 12..15 read A DIRECT from L2 (coalesced 2KB broadcasts, no
// barrier dependency) -- splits the A-stream across LDS and L2 pipes.
__global__ __launch_bounds__(256, 2) void sim_kernel(const uint8_t* __restrict__ zn8b,
                                                     float* __restrict__ pstats) {
    __shared__ __align__(16) char lds[2 * BUFSZ];
    const int tid  = threadIdx.x;
    const int w    = tid >> 6;
    const int l    = tid & 63;
    const int r32  = l & 31;
    const int h    = l >> 5;
    const int ib   = blockIdx.x >> 3;
    const int ch   = blockIdx.x & 7;
    const int i0w  = ib * 128 + w * 32;
    const int j0c  = ch * CHUNK_J;
    const int i_lane = i0w + r32;
    const int diag_jt = (ch == (ib >> 3)) ? ((ib & 7) * 4 + w) : -1;

    const char* ldsr = lds + l * 16;   // single LDS read base

#define GLL(SRC, DST) __builtin_amdgcn_global_load_lds(                         \
        (const __attribute__((address_space(1))) uint32_t*)(SRC),               \
        (__attribute__((address_space(3))) uint32_t*)(DST), 16, 0, 0)

    // stage tile 0 into buffer 0: wave w stages blocks m = 3w..3w+2
#pragma unroll
    for (int mm = 0; mm < 3; ++mm) {
        int m = w * 3 + mm;
        const uint8_t* s = zn8b + ((size_t)(ch * 32 + 0) * 16 + m) * 2048 + l * 16;
        char* d = lds + m * 2048;
        GLL(s, d);
        GLL(s + 1024, d + 1024);
    }

    // resident B-operand from blocked layout: I-tile = ib*4 + w (wave-uniform)
    i32x8 bres[16];
    {
        const uint8_t* rp = zn8b + (size_t)(ib * 4 + w) * 16 * 2048 + l * 16;
#pragma unroll
        for (int m = 0; m < 16; ++m) {
            *(long2_t*)&bres[m]       = *(const long2_t*)(rp + m * 2048);
            *((long2_t*)&bres[m] + 1) = *(const long2_t*)(rp + m * 2048 + 1024);
        }
    }

    float s0r = 0.f, s1r = 0.f;
    float b0 = NEG_BIG, b1 = NEG_BIG, b2 = NEG_BIG, b3 = NEG_BIG, b4 = NEG_BIG;

    __syncthreads();

#define TILE_BODY(JT, CUR) {                                                    \
        if ((JT) + 1 < NTILE) {                                                 \
            const size_t tb_ = ((size_t)(ch * 32 + (JT) + 1) * 16) * 2048;      \
            char* bufn_ = lds + ((CUR) ^ BUFSZ);                                \
            _Pragma("unroll")                                                   \
            for (int mm = 0; mm < 3; ++mm) {                                    \
                int m_ = w * 3 + mm;                                            \
                const uint8_t* s_ = zn8b + tb_ + m_ * 2048 + l * 16;            \
                char* d_ = bufn_ + m_ * 2048;                                   \
                GLL(s_, d_);                                                    \
                GLL(s_ + 1024, d_ + 1024);                                      \
            }                                                                   \
        }                                                                       \
        /* issue direct-L2 A loads for m 12..15 early */                        \
        const uint8_t* gs_ = zn8b + ((size_t)(ch * 32 + (JT)) * 16 + 12) * 2048 \
                             + l * 16;                                          \
        i32x8 g12, g13, g14, g15;                                               \
        *(long2_t*)&g12       = *(const long2_t*)(gs_);                         \
        *((long2_t*)&g12 + 1) = *(const long2_t*)(gs_ + 1024);                  \
        *(long2_t*)&g13       = *(const long2_t*)(gs_ + 2048);                  \
        *((long2_t*)&g13 + 1) = *(const long2_t*)(gs_ + 3072);                  \
        *(long2_t*)&g14       = *(const long2_t*)(gs_ + 4096);                  \
        *((long2_t*)&g14 + 1) = *(const long2_t*)(gs_ + 5120);                  \
        *(long2_t*)&g15       = *(const long2_t*)(gs_ + 6144);                  \
        *((long2_t*)&g15 + 1) = *(const long2_t*)(gs_ + 7168);                  \
        f32x16 acc0, acc1;                                                      \
        _Pragma("unroll")                                                       \
        for (int r = 0; r < 16; ++r) { acc0[r] = 0.f; acc1[r] = 0.f; }          \
        __builtin_amdgcn_s_setprio(1);                                          \
        _Pragma("unroll")                                                       \
        for (int m = 0; m < 12; ++m) {                                          \
            asm volatile("" : "+v"(bres[m]));  /* keep resident */              \
            i32x8 a;                                                            \
            *(long2_t*)&a       = *(const long2_t*)(ldsr + (CUR) + m * 2048);   \
            *((long2_t*)&a + 1) = *(const long2_t*)(ldsr + (CUR) + m * 2048 + 1024);\
            if (m & 1)                                                          \
                acc1 = __builtin_amdgcn_mfma_scale_f32_32x32x64_f8f6f4(         \
                    a, bres[m], acc1, 0, 0, 0, 127, 0, 127);                    \
            else                                                                \
                acc0 = __builtin_amdgcn_mfma_scale_f32_32x32x64_f8f6f4(         \
                    a, bres[m], acc0, 0, 0, 0, 127, 0, 127);                    \
        }                                                                       \
        asm volatile("" : "+v"(bres[12]), "+v"(bres[13]),                       \
                          "+v"(bres[14]), "+v"(bres[15]));                      \
        acc0 = __builtin_amdgcn_mfma_scale_f32_32x32x64_f8f6f4(                 \
            g12, bres[12], acc0, 0, 0, 0, 127, 0, 127);                         \
        acc1 = __builtin_amdgcn_mfma_scale_f32_32x32x64_f8f6f4(                 \
            g13, bres[13], acc1, 0, 0, 0, 127, 0, 127);                         \
        acc0 = __builtin_amdgcn_mfma_scale_f32_32x32x64_f8f6f4(                 \
            g14, bres[14], acc0, 0, 0, 0, 127, 0, 127);                         \
        acc1 = __builtin_amdgcn_mfma_scale_f32_32x32x64_f8f6f4(                 \
            g15, bres[15], acc1, 0, 0, 0, 127, 0, 127);                         \
        __builtin_amdgcn_s_setprio(0);                                          \
        if ((JT) != diag_jt) {                                                  \
            _Pragma("unroll")                                                   \
            for (int r = 0; r < 16; ++r) {                                      \
                float v = acc0[r] + acc1[r];                                    \
                INS5(b0, b1, b2, b3, b4, v);                                    \
                float e_; EXPRAW(e_, v);                                        \
                if (r & 1) s1r += e_; else s0r += e_;                           \
            }                                                                   \
        } else {                                                                \
            const int dd2 = i_lane - (j0c + (JT) * 32) - 4 * h;                 \
            _Pragma("unroll")                                                   \
            for (int r = 0; r < 16; ++r) {                                      \
                const int jm = (r & 3) + 8 * (r >> 2);                          \
                float v = acc0[r] + acc1[r];                                    \
                if (dd2 == jm) v = NEG_BIG;                                     \
                INS5(b0, b1, b2, b3, b4, v);                                    \
                float e_; EXPRAW(e_, v);                                        \
                if (r & 1) s1r += e_; else s0r += e_;                           \
            }                                                                   \
        }                                                                       \
        __syncthreads();                                                        \
    }

    for (int jt = 0; jt < NTILE; jt += 2) {
        TILE_BODY(jt, 0);
        TILE_BODY(jt + 1, BUFSZ);
    }
#undef TILE_BODY
#undef GLL

    float s_run = s0r + s1r;
    // merge the two h-halves: lanes l and l^32 hold complementary j-rows of col i
    s_run += __shfl_xor(s_run, 32);
    {
        float o0 = __shfl_xor(b0, 32), o1 = __shfl_xor(b1, 32), o2 = __shfl_xor(b2, 32),
              o3 = __shfl_xor(b3, 32), o4 = __shfl_xor(b4, 32);
        INS5(b0, b1, b2, b3, b4, o0); INS5(b0, b1, b2, b3, b4, o1);
        INS5(b0, b1, b2, b3, b4, o2); INS5(b0, b1, b2, b3, b4, o3);
        INS5(b0, b1, b2, b3, b4, o4);
    }
    if (h == 0) {
        float* p = pstats + ((size_t)ch * N_ROWS + i_lane) * 8;
        p[0] = s_run; p[1] = b0; p[2] = b1; p[3] = b2; p[4] = b3; p[5] = b4;
        p[6] = 0.f; p[7] = 0.f;
    }
}

// ---------------- K3: per-row merge of 8 chunk partials ----------------
__global__ __launch_bounds__(128) void reduce1(const float* __restrict__ pstats,
                                               float* __restrict__ partial) {
    int row = blockIdx.x * 128 + threadIdx.x;
    float S = 0.f;
    float b0 = NEG_BIG, b1 = NEG_BIG, b2 = NEG_BIG, b3 = NEG_BIG, b4 = NEG_BIG;
#pragma unroll
    for (int c = 0; c < NCHUNK; ++c) {
        const float* p = pstats + ((size_t)c * N_ROWS + row) * 8;
        S += p[0];
        float v0 = p[1], v1 = p[2], v2 = p[3], v3 = p[4], v4 = p[5];
        INS5(b0, b1, b2, b3, b4, v0); INS5(b0, b1, b2, b3, b4, v1);
        INS5(b0, b1, b2, b3, b4, v2); INS5(b0, b1, b2, b3, b4, v3);
        INS5(b0, b1, b2, b3, b4, v4);
    }
    float e0, e1, e2, e3, e4;
    EXPRAW(e0, b0); EXPRAW(e1, b1); EXPRAW(e2, b2); EXPRAW(e3, b3); EXPRAW(e4, b4);
    float S5 = e0 + e1 + e2 + e3 + e4;
    float loss = __logf(S) - __logf(S5);
#pragma unroll
    for (int m = 1; m < 64; m <<= 1) loss += __shfl_xor(loss, m);
    __shared__ float rr[2];
    if ((threadIdx.x & 63) == 0) rr[threadIdx.x >> 6] = loss;
    __syncthreads();
    if (threadIdx.x == 0) partial[blockIdx.x] = rr[0] + rr[1];
}

// ---------------- K4: final mean ----------------
__global__ void reduce2(const float* __restrict__ partial, float* __restrict__ out) {
    float v = partial[threadIdx.x];   // 64 partials
#pragma unroll
    for (int m = 1; m < 64; m <<= 1) v += __shfl_xor(v, m);
    if (threadIdx.x == 0) out[0] = v * (1.0f / N_ROWS);
}

extern "C" void kernel_launch(void* const* d_in, const int* in_sizes, int n_in,
                              void* d_out, int out_size, void* d_ws, size_t ws_size,
                              hipStream_t stream) {
    const float* z = (const float*)d_in[0];
    float* out = (float*)d_out;
    uint8_t* zn8b  = (uint8_t*)d_ws;                                   // 8 MB blocked
    float* pstats  = (float*)((char*)d_ws + (size_t)8 * 1024 * 1024);  // 2 MB
    float* partial = (float*)((char*)d_ws + (size_t)10 * 1024 * 1024); // 256 B

    norm_kernel<<<N_ROWS / 4, 256, 0, stream>>>(z, zn8b);
    sim_kernel<<<64 * NCHUNK, 256, 0, stream>>>(zn8b, pstats);
    reduce1<<<N_ROWS / 128, 128, 0, stream>>>(pstats, partial);
    reduce2<<<1, 64, 0, stream>>>(partial, out);
}

// Round 14
// 69.864 us; speedup vs baseline: 2.3357x; 1.2789x over previous
//
#include <hip/hip_runtime.h>
#include <stdint.h>

#define N_ROWS 8192
#define D_DIM  1024
#define NEG_BIG -1e30f
#define NCHUNK 32
#define CHUNK_J 256
#define NTILE 8               // 8 j-tiles of 32 cols per chunk
#define BUFSZ 17408           // 16 KB fp4 tile + 1 KB scale block

typedef __attribute__((ext_vector_type(16))) float f32x16;
typedef __attribute__((ext_vector_type(8)))  int   i32x8;
typedef __attribute__((ext_vector_type(4)))  int   i32x4;
typedef __attribute__((ext_vector_type(2)))  long  long2_t;

// exp(10v - 10) = exp2(v*C - C), raw v_exp_f32
#define EXPC 14.4269504089f
#define EXPRAW(dst, v) { float _a = fmaf((v), EXPC, -EXPC);                 \
    asm("v_exp_f32 %0, %1" : "=v"(dst) : "v"(_a)); }

// branchless sorted insert of v into descending 5-list, med3 form
#define INS5(b0,b1,b2,b3,b4,v) {                        \
    float _n4 = __builtin_amdgcn_fmed3f(b3, (v), b4);   \
    float _n3 = __builtin_amdgcn_fmed3f(b2, (v), b3);   \
    float _n2 = __builtin_amdgcn_fmed3f(b1, (v), b2);   \
    float _n1 = __builtin_amdgcn_fmed3f(b0, (v), b1);   \
    b0 = fmaxf(b0, (v)); b1 = _n1; b2 = _n2; b3 = _n3; b4 = _n4; }

// e2m1 encode of x (pre-scaled by inv = 2^-s): grid {0,.5,1,1.5,2,3,4,6}
static __device__ inline uint32_t enc4(float x, float inv) {
    float q = fabsf(x) * inv;
    uint32_t n = q < 0.25f ? 0u : (q < 0.75f ? 1u : (q < 1.25f ? 2u : (q < 1.75f ? 3u :
                 (q < 2.5f  ? 4u : (q < 3.5f  ? 5u : (q < 5.0f  ? 6u : 7u))))));
    return n | (x < 0.f ? 8u : 0u);
}

// ---------------- K1: normalize -> MX-fp4 (e2m1 + per-32-block E8M0) --------
// Data: block(J,m) = 1024 B at zn4+(J*16+m)*1024 = rows J*32..+31, k in
// [64m,64m+64). Fragment lane l' = (row&31)+32*((k>>5)&1); element k at
// nibble (k&31) of the 16 B at l'*16 (low nibble first).
// Scales: sbq+J*1024+l'*16+b = E8M0 for (row l'&31, k-block 2b+(l'>>5)) --
// i.e. byte b of a lane's scale vector is the scale for MFMA m=b.
__global__ __launch_bounds__(256) void norm_kernel(const float* __restrict__ z,
                                                   uint8_t* __restrict__ zn4,
                                                   uint8_t* __restrict__ sbq) {
    int wave = threadIdx.x >> 6;
    int lane = threadIdx.x & 63;
    int row  = blockIdx.x * 4 + wave;
    const float* zr = z + (size_t)row * D_DIM;
    float4 c[4];
    float ss = 0.f;
#pragma unroll
    for (int i = 0; i < 4; ++i) {
        c[i] = *(const float4*)(zr + i * 256 + lane * 4);
        ss += c[i].x*c[i].x + c[i].y*c[i].y + c[i].z*c[i].z + c[i].w*c[i].w;
    }
#pragma unroll
    for (int m = 1; m < 64; m <<= 1) ss += __shfl_xor(ss, m);
    float scale = 1.0f / fmaxf(sqrtf(ss), 1e-12f);
    const int J = row >> 5, r31 = row & 31;
    uint8_t* db = zn4 + (size_t)J * 16384;
    uint8_t* sb = sbq + (size_t)J * 1024;
#pragma unroll
    for (int i = 0; i < 4; ++i) {
        float x0 = c[i].x*scale, x1 = c[i].y*scale, x2 = c[i].z*scale, x3 = c[i].w*scale;
        float am = fmaxf(fmaxf(fabsf(x0), fabsf(x1)), fmaxf(fabsf(x2), fabsf(x3)));
        am = fmaxf(am, __shfl_xor(am, 1));
        am = fmaxf(am, __shfl_xor(am, 2));
        am = fmaxf(am, __shfl_xor(am, 4));
        uint32_t ub = __float_as_uint(am);
        int sbyte = (int)(ub >> 23) - 2 + (((ub & 0x7fffffu) > 0x400000u) ? 1 : 0);
        float inv = __uint_as_float((uint32_t)(254 - sbyte) << 23);   // 2^-s
        uint32_t pk = enc4(x0, inv) | (enc4(x1, inv) << 4)
                    | (enc4(x2, inv) << 8) | (enc4(x3, inv) << 12);
        int m  = i * 4 + (lane >> 4);
        int l2 = r31 + 32 * ((lane >> 3) & 1);
        *(uint16_t*)(db + m * 1024 + l2 * 16 + 2 * (lane & 7)) = (uint16_t)pk;
        if ((lane & 7) == 0) {
            int j = lane >> 3;
            sb[(size_t)(r31 + 32 * (j & 1)) * 16 + i * 4 + (j >> 1)] = (uint8_t)sbyte;
        }
    }
}

// ---------------- K2: fused MX-fp4 sim via scale-MFMA K=64 -------------------
// grid: 64 i-blocks (128 rows, 32/wave) x 32 j-chunks (256 cols, 8 tiles).
// bres8[g]: even m=2g in lower 4 dwords, odd m=2g+1 in upper (fp4 reads only
// the lower 4 -> odd m copied into btmp). 64 resident VGPRs -> 3 waves/SIMD.
// Scales staged with the tile (1 KB); opsel (literal M&3) picks E8M0 byte.
__global__ __launch_bounds__(256, 3) void sim_kernel(const uint8_t* __restrict__ zn4,
                                                     const uint8_t* __restrict__ sbq,
                                                     float* __restrict__ pstats) {
    __shared__ __align__(16) char lds[2 * BUFSZ];
    const int tid  = threadIdx.x;
    const int w    = tid >> 6;
    const int l    = tid & 63;
    const int r32  = l & 31;
    const int h    = l >> 5;
    const int ib   = blockIdx.x >> 5;
    const int ch   = blockIdx.x & 31;
    const int i0w  = ib * 128 + w * 32;
    const int j0c  = ch * CHUNK_J;
    const int i_lane = i0w + r32;
    const int Ii   = ib * 4 + w;                       // i-tile index 0..255
    const int diag_jt = ((Ii >> 3) == ch) ? (Ii & 7) : -1;
    const char* ldsr = lds + l * 16;

#define GLL(SRC, DST) __builtin_amdgcn_global_load_lds(                         \
        (const __attribute__((address_space(1))) uint32_t*)(SRC),               \
        (__attribute__((address_space(3))) uint32_t*)(DST), 16, 0, 0)

#define STAGE(JTN, BUF) {                                                       \
        const uint8_t* sD_ = zn4 + (size_t)(ch * NTILE + (JTN)) * 16384;        \
        _Pragma("unroll")                                                       \
        for (int mm = 0; mm < 4; ++mm) {                                        \
            int m_ = w * 4 + mm;                                                \
            GLL(sD_ + m_ * 1024 + l * 16, (BUF) + m_ * 1024);                   \
        }                                                                       \
        if (w == 0)                                                             \
            GLL(sbq + (size_t)(ch * NTILE + (JTN)) * 1024 + l * 16,             \
                (BUF) + 16384);                                                 \
    }

    STAGE(0, lds);

    // resident B: 8 packed pairs + 4 scale words
    i32x8 bres8[8];
    {
        const uint8_t* rp = zn4 + (size_t)Ii * 16384 + l * 16;
#pragma unroll
        for (int g = 0; g < 8; ++g) {
            *(long2_t*)&bres8[g]       = *(const long2_t*)(rp + (2 * g) * 1024);
            *((long2_t*)&bres8[g] + 1) = *(const long2_t*)(rp + (2 * g + 1) * 1024);
        }
    }
    uint32_t sb_[4];
    {
        const uint32_t* sp = (const uint32_t*)(sbq + (size_t)Ii * 1024 + l * 16);
        sb_[0] = sp[0]; sb_[1] = sp[1]; sb_[2] = sp[2]; sb_[3] = sp[3];
    }

    float s0r = 0.f, s1r = 0.f;
    float b0 = NEG_BIG, b1 = NEG_BIG, b2 = NEG_BIG, b3 = NEG_BIG, b4 = NEG_BIG;
    i32x8 areg0 = {0,0,0,0,0,0,0,0}, areg1 = {0,0,0,0,0,0,0,0};
    i32x8 btmp  = {0,0,0,0,0,0,0,0};

    __syncthreads();

// literal-M MFMA macros: opsel args (M)&3 are integer constant expressions
#define MFMA_E(M) {                                                             \
        asm volatile("" : "+v"(bres8[(M) >> 1]));                               \
        *(long2_t*)&areg0 = *(const long2_t*)(ldst_ + (M) * 1024);              \
        acc0 = __builtin_amdgcn_mfma_scale_f32_32x32x64_f8f6f4(                 \
            areg0, bres8[(M) >> 1], acc0, 4, 4,                                 \
            (M) & 3, sa_[(M) >> 2], (M) & 3, sb_[(M) >> 2]); }
#define MFMA_O(M) {                                                             \
        *(long2_t*)&btmp  = *((const long2_t*)&bres8[(M) >> 1] + 1);            \
        *(long2_t*)&areg1 = *(const long2_t*)(ldst_ + (M) * 1024);              \
        acc1 = __builtin_amdgcn_mfma_scale_f32_32x32x64_f8f6f4(                 \
            areg1, btmp, acc1, 4, 4,                                            \
            (M) & 3, sa_[(M) >> 2], (M) & 3, sb_[(M) >> 2]); }

#define TILE_BODY(JT, CUR) {                                                    \
        if ((JT) + 1 < NTILE) STAGE((JT) + 1, lds + ((CUR) ^ BUFSZ));           \
        const char* ldst_ = ldsr + (CUR);                                       \
        uint32_t sa_[4];                                                        \
        {                                                                       \
            i32x4 sv = *(const i32x4*)(lds + (CUR) + 16384 + l * 16);           \
            sa_[0] = sv[0]; sa_[1] = sv[1]; sa_[2] = sv[2]; sa_[3] = sv[3];     \
        }                                                                       \
        f32x16 acc0, acc1;                                                      \
        _Pragma("unroll")                                                       \
        for (int r = 0; r < 16; ++r) { acc0[r] = 0.f; acc1[r] = 0.f; }          \
        __builtin_amdgcn_s_setprio(1);                                          \
        MFMA_E(0)  MFMA_O(1)  MFMA_E(2)  MFMA_O(3)                              \
        MFMA_E(4)  MFMA_O(5)  MFMA_E(6)  MFMA_O(7)                              \
        MFMA_E(8)  MFMA_O(9)  MFMA_E(10) MFMA_O(11)                             \
        MFMA_E(12) MFMA_O(13) MFMA_E(14) MFMA_O(15)                             \
        __builtin_amdgcn_s_setprio(0);                                          \
        if ((JT) != diag_jt) {                                                  \
            _Pragma("unroll")                                                   \
            for (int r = 0; r < 16; ++r) {                                      \
                float v = acc0[r] + acc1[r];                                    \
                INS5(b0, b1, b2, b3, b4, v);                                    \
                float e_; EXPRAW(e_, v);                                        \
                if (r & 1) s1r += e_; else s0r += e_;                           \
            }                                                                   \
        } else {                                                                \
            const int dd2 = i_lane - (j0c + (JT) * 32) - 4 * h;                 \
            _Pragma("unroll")                                                   \
            for (int r = 0; r < 16; ++r) {                                      \
                const int jm = (r & 3) + 8 * (r >> 2);                          \
                float v = acc0[r] + acc1[r];                                    \
                if (dd2 == jm) v = NEG_BIG;                                     \
                INS5(b0, b1, b2, b3, b4, v);                                    \
                float e_; EXPRAW(e_, v);                                        \
                if (r & 1) s1r += e_; else s0r += e_;                           \
            }                                                                   \
        }                                                                       \
        __syncthreads();                                                        \
    }

    for (int jt = 0; jt < NTILE; jt += 2) {
        TILE_BODY(jt, 0);
        TILE_BODY(jt + 1, BUFSZ);
    }
#undef TILE_BODY
#undef MFMA_E
#undef MFMA_O
#undef STAGE
#undef GLL

    float s_run = s0r + s1r;
    s_run += __shfl_xor(s_run, 32);
    {
        float o0 = __shfl_xor(b0, 32), o1 = __shfl_xor(b1, 32), o2 = __shfl_xor(b2, 32),
              o3 = __shfl_xor(b3, 32), o4 = __shfl_xor(b4, 32);
        INS5(b0, b1, b2, b3, b4, o0); INS5(b0, b1, b2, b3, b4, o1);
        INS5(b0, b1, b2, b3, b4, o2); INS5(b0, b1, b2, b3, b4, o3);
        INS5(b0, b1, b2, b3, b4, o4);
    }
    if (h == 0) {
        float* p = pstats + ((size_t)ch * N_ROWS + i_lane) * 8;
        p[0] = s_run; p[1] = b0; p[2] = b1; p[3] = b2; p[4] = b3; p[5] = b4;
        p[6] = 0.f; p[7] = 0.f;
    }
}

// ---------------- K3: per-row merge of 32 chunk partials ----------------
__global__ __launch_bounds__(128) void reduce1(const float* __restrict__ pstats,
                                               float* __restrict__ partial) {
    int row = blockIdx.x * 128 + threadIdx.x;
    float S = 0.f;
    float b0 = NEG_BIG, b1 = NEG_BIG, b2 = NEG_BIG, b3 = NEG_BIG, b4 = NEG_BIG;
#pragma unroll
    for (int c = 0; c < NCHUNK; ++c) {
        const float* p = pstats + ((size_t)c * N_ROWS + row) * 8;
        S += p[0];
        float v0 = p[1], v1 = p[2], v2 = p[3], v3 = p[4], v4 = p[5];
        INS5(b0, b1, b2, b3, b4, v0); INS5(b0, b1, b2, b3, b4, v1);
        INS5(b0, b1, b2, b3, b4, v2); INS5(b0, b1, b2, b3, b4, v3);
        INS5(b0, b1, b2, b3, b4, v4);
    }
    float e0, e1, e2, e3, e4;
    EXPRAW(e0, b0); EXPRAW(e1, b1); EXPRAW(e2, b2); EXPRAW(e3, b3); EXPRAW(e4, b4);
    float S5 = e0 + e1 + e2 + e3 + e4;
    float loss = __logf(S) - __logf(S5);
#pragma unroll
    for (int m = 1; m < 64; m <<= 1) loss += __shfl_xor(loss, m);
    __shared__ float rr[2];
    if ((threadIdx.x & 63) == 0) rr[threadIdx.x >> 6] = loss;
    __syncthreads();
    if (threadIdx.x == 0) partial[blockIdx.x] = rr[0] + rr[1];
}

// ---------------- K4: final mean ----------------
__global__ void reduce2(const float* __restrict__ partial, float* __restrict__ out) {
    float v = partial[threadIdx.x];   // 64 partials
#pragma unroll
    for (int m = 1; m < 64; m <<= 1) v += __shfl_xor(v, m);
    if (threadIdx.x == 0) out[0] = v * (1.0f / N_ROWS);
}

extern "C" void kernel_launch(void* const* d_in, const int* in_sizes, int n_in,
                              void* d_out, int out_size, void* d_ws, size_t ws_size,
                              hipStream_t stream) {
    const float* z = (const float*)d_in[0];
    float* out = (float*)d_out;
    uint8_t* zn4   = (uint8_t*)d_ws;                                     // 4 MB
    uint8_t* sbq   = (uint8_t*)d_ws + (size_t)4 * 1024 * 1024;           // 256 KB
    float* pstats  = (float*)((char*)d_ws + (size_t)4608 * 1024);        // 8 MB
    float* partial = (float*)((char*)d_ws + (size_t)13 * 1024 * 1024);   // 256 B

    norm_kernel<<<N_ROWS / 4, 256, 0, stream>>>(z, zn4, sbq);
    sim_kernel<<<64 * NCHUNK, 256, 0, stream>>>(zn4, sbq, pstats);
    reduce1<<<N_ROWS / 128, 128, 0, stream>>>(pstats, partial);
    reduce2<<<1, 64, 0, stream>>>(partial, out);
}

// Round 16
// 66.193 us; speedup vs baseline: 2.4653x; 1.0555x over previous
//
#include <hip/hip_runtime.h>
#include <stdint.h>

#define N_ROWS 8192
#define D_DIM  1024
#define NEG_BIG -1e30f
#define NCHUNK 16
#define CHUNK_J 512
#define NTILE 16              // 16 j-tiles of 32 cols per chunk
#define BUFSZ 17408           // 16 KB fp4 tile + 1 KB scale block

typedef __attribute__((ext_vector_type(16))) float f32x16;
typedef __attribute__((ext_vector_type(8)))  int   i32x8;
typedef __attribute__((ext_vector_type(4)))  int   i32x4;
typedef __attribute__((ext_vector_type(2)))  long  long2_t;

// exp(10v - 10) = exp2(v*C - C), raw v_exp_f32
#define EXPC 14.4269504089f
#define EXPRAW(dst, v) { float _a = fmaf((v), EXPC, -EXPC);                 \
    asm("v_exp_f32 %0, %1" : "=v"(dst) : "v"(_a)); }

// branchless sorted insert of v into descending 5-list, med3 form
#define INS5(b0,b1,b2,b3,b4,v) {                        \
    float _n4 = __builtin_amdgcn_fmed3f(b3, (v), b4);   \
    float _n3 = __builtin_amdgcn_fmed3f(b2, (v), b3);   \
    float _n2 = __builtin_amdgcn_fmed3f(b1, (v), b2);   \
    float _n1 = __builtin_amdgcn_fmed3f(b0, (v), b1);   \
    b0 = fmaxf(b0, (v)); b1 = _n1; b2 = _n2; b3 = _n3; b4 = _n4; }

// e2m1 encode of x (pre-scaled by inv = 2^-s): grid {0,.5,1,1.5,2,3,4,6}
static __device__ inline uint32_t enc4(float x, float inv) {
    float q = fabsf(x) * inv;
    uint32_t n = q < 0.25f ? 0u : (q < 0.75f ? 1u : (q < 1.25f ? 2u : (q < 1.75f ? 3u :
                 (q < 2.5f  ? 4u : (q < 3.5f  ? 5u : (q < 5.0f  ? 6u : 7u))))));
    return n | (x < 0.f ? 8u : 0u);
}

// ---------------- K1: normalize -> MX-fp4 (e2m1 + per-32-block E8M0) --------
__global__ __launch_bounds__(256) void norm_kernel(const float* __restrict__ z,
                                                   uint8_t* __restrict__ zn4,
                                                   uint8_t* __restrict__ sbq) {
    int wave = threadIdx.x >> 6;
    int lane = threadIdx.x & 63;
    int row  = blockIdx.x * 4 + wave;
    const float* zr = z + (size_t)row * D_DIM;
    float4 c[4];
    float ss = 0.f;
#pragma unroll
    for (int i = 0; i < 4; ++i) {
        c[i] = *(const float4*)(zr + i * 256 + lane * 4);
        ss += c[i].x*c[i].x + c[i].y*c[i].y + c[i].z*c[i].z + c[i].w*c[i].w;
    }
#pragma unroll
    for (int m = 1; m < 64; m <<= 1) ss += __shfl_xor(ss, m);
    float scale = 1.0f / fmaxf(sqrtf(ss), 1e-12f);
    const int J = row >> 5, r31 = row & 31;
    uint8_t* db = zn4 + (size_t)J * 16384;
    uint8_t* sb = sbq + (size_t)J * 1024;
#pragma unroll
    for (int i = 0; i < 4; ++i) {
        float x0 = c[i].x*scale, x1 = c[i].y*scale, x2 = c[i].z*scale, x3 = c[i].w*scale;
        float am = fmaxf(fmaxf(fabsf(x0), fabsf(x1)), fmaxf(fabsf(x2), fabsf(x3)));
        am = fmaxf(am, __shfl_xor(am, 1));
        am = fmaxf(am, __shfl_xor(am, 2));
        am = fmaxf(am, __shfl_xor(am, 4));
        uint32_t ub = __float_as_uint(am);
        int sbyte = (int)(ub >> 23) - 2 + (((ub & 0x7fffffu) > 0x400000u) ? 1 : 0);
        float inv = __uint_as_float((uint32_t)(254 - sbyte) << 23);   // 2^-s
        uint32_t pk = enc4(x0, inv) | (enc4(x1, inv) << 4)
                    | (enc4(x2, inv) << 8) | (enc4(x3, inv) << 12);
        int m  = i * 4 + (lane >> 4);
        int l2 = r31 + 32 * ((lane >> 3) & 1);
        *(uint16_t*)(db + m * 1024 + l2 * 16 + 2 * (lane & 7)) = (uint16_t)pk;
        if ((lane & 7) == 0) {
            int j = lane >> 3;
            sb[(size_t)(r31 + 32 * (j & 1)) * 16 + i * 4 + (j >> 1)] = (uint8_t)sbyte;
        }
    }
}

// ---------------- K2: fused MX-fp4 sim, TWO resident i-sets ------------------
// grid: 32 i-blocks (256 rows: setA = ib*256+w*32, setB = +128) x 16 j-chunks
// (512 cols, 16 tiles). Each staged A-fragment read feeds 2 MFMAs (setA+setB,
// alternating accA/accB = 2 independent chains). LDS reads per MFMA halve;
// MFMA becomes the pole. 2 blocks/CU exactly (512 blocks), 2 waves/SIMD.
__global__ __launch_bounds__(256, 2) void sim_kernel(const uint8_t* __restrict__ zn4,
                                                     const uint8_t* __restrict__ sbq,
                                                     float* __restrict__ pstats) {
    __shared__ __align__(16) char lds[2 * BUFSZ];
    const int tid  = threadIdx.x;
    const int w    = tid >> 6;
    const int l    = tid & 63;
    const int r32  = l & 31;
    const int h    = l >> 5;
    const int ib   = blockIdx.x >> 4;
    const int ch   = blockIdx.x & 15;
    const int j0c  = ch * CHUNK_J;
    const int i_laneA = ib * 256 + w * 32 + r32;
    const int i_laneB = i_laneA + 128;
    const int IiA  = ib * 8 + w;
    const int IiB  = IiA + 4;
    const int diag_jtA = ((IiA >> 4) == ch) ? (IiA & 15) : -1;
    const int diag_jtB = ((IiB >> 4) == ch) ? (IiB & 15) : -1;
    const char* ldsr = lds + l * 16;

#define GLL(SRC, DST) __builtin_amdgcn_global_load_lds(                         \
        (const __attribute__((address_space(1))) uint32_t*)(SRC),               \
        (__attribute__((address_space(3))) uint32_t*)(DST), 16, 0, 0)

#define STAGE(JTN, BUF) {                                                       \
        const uint8_t* sD_ = zn4 + (size_t)(ch * NTILE + (JTN)) * 16384;        \
        _Pragma("unroll")                                                       \
        for (int mm = 0; mm < 4; ++mm) {                                        \
            int m_ = w * 4 + mm;                                                \
            GLL(sD_ + m_ * 1024 + l * 16, (BUF) + m_ * 1024);                   \
        }                                                                       \
        if (w == 0)                                                             \
            GLL(sbq + (size_t)(ch * NTILE + (JTN)) * 1024 + l * 16,             \
                (BUF) + 16384);                                                 \
    }

    STAGE(0, lds);

    // resident B-operands, packed pairs (even m lower 4 dwords, odd m upper)
    i32x8 bresA[8], bresB[8];
    {
        const uint8_t* rpA = zn4 + (size_t)IiA * 16384 + l * 16;
        const uint8_t* rpB = zn4 + (size_t)IiB * 16384 + l * 16;
#pragma unroll
        for (int g = 0; g < 8; ++g) {
            *(long2_t*)&bresA[g]       = *(const long2_t*)(rpA + (2 * g) * 1024);
            *((long2_t*)&bresA[g] + 1) = *(const long2_t*)(rpA + (2 * g + 1) * 1024);
            *(long2_t*)&bresB[g]       = *(const long2_t*)(rpB + (2 * g) * 1024);
            *((long2_t*)&bresB[g] + 1) = *(const long2_t*)(rpB + (2 * g + 1) * 1024);
        }
    }
    uint32_t swA_[4], swB_[4];
    {
        const uint32_t* spA = (const uint32_t*)(sbq + (size_t)IiA * 1024 + l * 16);
        const uint32_t* spB = (const uint32_t*)(sbq + (size_t)IiB * 1024 + l * 16);
        swA_[0] = spA[0]; swA_[1] = spA[1]; swA_[2] = spA[2]; swA_[3] = spA[3];
        swB_[0] = spB[0]; swB_[1] = spB[1]; swB_[2] = spB[2]; swB_[3] = spB[3];
    }

    float sumA = 0.f, sumB = 0.f;
    float a0 = NEG_BIG, a1 = NEG_BIG, a2 = NEG_BIG, a3 = NEG_BIG, a4 = NEG_BIG;
    float c0 = NEG_BIG, c1 = NEG_BIG, c2 = NEG_BIG, c3 = NEG_BIG, c4 = NEG_BIG;
    i32x8 areg = {0,0,0,0,0,0,0,0};
    i32x8 btmp = {0,0,0,0,0,0,0,0};

    __syncthreads();

// one A-fragment read feeds both sets; opsel args are literal constants
#define MFMA2_E(M) {                                                            \
        asm volatile("" : "+v"(bresA[(M) >> 1]), "+v"(bresB[(M) >> 1]));        \
        *(long2_t*)&areg = *(const long2_t*)(ldst_ + (M) * 1024);               \
        accA = __builtin_amdgcn_mfma_scale_f32_32x32x64_f8f6f4(                 \
            areg, bresA[(M) >> 1], accA, 4, 4,                                  \
            (M) & 3, sa_[(M) >> 2], (M) & 3, swA_[(M) >> 2]);                   \
        accB = __builtin_amdgcn_mfma_scale_f32_32x32x64_f8f6f4(                 \
            areg, bresB[(M) >> 1], accB, 4, 4,                                  \
            (M) & 3, sa_[(M) >> 2], (M) & 3, swB_[(M) >> 2]); }
#define MFMA2_O(M) {                                                            \
        *(long2_t*)&areg = *(const long2_t*)(ldst_ + (M) * 1024);               \
        *(long2_t*)&btmp = *((const long2_t*)&bresA[(M) >> 1] + 1);             \
        accA = __builtin_amdgcn_mfma_scale_f32_32x32x64_f8f6f4(                 \
            areg, btmp, accA, 4, 4,                                             \
            (M) & 3, sa_[(M) >> 2], (M) & 3, swA_[(M) >> 2]);                   \
        *(long2_t*)&btmp = *((const long2_t*)&bresB[(M) >> 1] + 1);             \
        accB = __builtin_amdgcn_mfma_scale_f32_32x32x64_f8f6f4(                 \
            areg, btmp, accB, 4, 4,                                             \
            (M) & 3, sa_[(M) >> 2], (M) & 3, swB_[(M) >> 2]); }

#define EPIL(JT, ACC, D0, D1, D2, D3, D4, SUM, DJT, ILANE) {                    \
        if ((JT) != (DJT)) {                                                    \
            _Pragma("unroll")                                                   \
            for (int r = 0; r < 16; ++r) {                                      \
                float v = (ACC)[r];                                             \
                INS5(D0, D1, D2, D3, D4, v);                                    \
                float e_; EXPRAW(e_, v);                                        \
                SUM += e_;                                                      \
            }                                                                   \
        } else {                                                                \
            const int dd2 = (ILANE) - (j0c + (JT) * 32) - 4 * h;                \
            _Pragma("unroll")                                                   \
            for (int r = 0; r < 16; ++r) {                                      \
                const int jm = (r & 3) + 8 * (r >> 2);                          \
                float v = (ACC)[r];                                             \
                if (dd2 == jm) v = NEG_BIG;                                     \
                INS5(D0, D1, D2, D3, D4, v);                                    \
                float e_; EXPRAW(e_, v);                                        \
                SUM += e_;                                                      \
            }                                                                   \
        }                                                                       \
    }

#define TILE_BODY(JT, CUR) {                                                    \
        if ((JT) + 1 < NTILE) STAGE((JT) + 1, lds + ((CUR) ^ BUFSZ));           \
        const char* ldst_ = ldsr + (CUR);                                       \
        uint32_t sa_[4];                                                        \
        {                                                                       \
            i32x4 sv = *(const i32x4*)(lds + (CUR) + 16384 + l * 16);           \
            sa_[0] = sv[0]; sa_[1] = sv[1]; sa_[2] = sv[2]; sa_[3] = sv[3];     \
        }                                                                       \
        f32x16 accA, accB;                                                      \
        _Pragma("unroll")                                                       \
        for (int r = 0; r < 16; ++r) { accA[r] = 0.f; accB[r] = 0.f; }          \
        __builtin_amdgcn_s_setprio(1);                                          \
        MFMA2_E(0)  MFMA2_O(1)  MFMA2_E(2)  MFMA2_O(3)                          \
        MFMA2_E(4)  MFMA2_O(5)  MFMA2_E(6)  MFMA2_O(7)                          \
        MFMA2_E(8)  MFMA2_O(9)  MFMA2_E(10) MFMA2_O(11)                         \
        MFMA2_E(12) MFMA2_O(13) MFMA2_E(14) MFMA2_O(15)                         \
        __builtin_amdgcn_s_setprio(0);                                          \
        EPIL(JT, accA, a0, a1, a2, a3, a4, sumA, diag_jtA, i_laneA)             \
        EPIL(JT, accB, c0, c1, c2, c3, c4, sumB, diag_jtB, i_laneB)             \
        __syncthreads();                                                        \
    }

    for (int jt = 0; jt < NTILE; jt += 2) {
        TILE_BODY(jt, 0);
        TILE_BODY(jt + 1, BUFSZ);
    }
#undef TILE_BODY
#undef EPIL
#undef MFMA2_E
#undef MFMA2_O
#undef STAGE
#undef GLL

    // merge the two h-halves (lanes l, l^32 hold complementary j-rows)
    sumA += __shfl_xor(sumA, 32);
    sumB += __shfl_xor(sumB, 32);
    {
        float o0 = __shfl_xor(a0, 32), o1 = __shfl_xor(a1, 32), o2 = __shfl_xor(a2, 32),
              o3 = __shfl_xor(a3, 32), o4 = __shfl_xor(a4, 32);
        INS5(a0, a1, a2, a3, a4, o0); INS5(a0, a1, a2, a3, a4, o1);
        INS5(a0, a1, a2, a3, a4, o2); INS5(a0, a1, a2, a3, a4, o3);
        INS5(a0, a1, a2, a3, a4, o4);
    }
    {
        float o0 = __shfl_xor(c0, 32), o1 = __shfl_xor(c1, 32), o2 = __shfl_xor(c2, 32),
              o3 = __shfl_xor(c3, 32), o4 = __shfl_xor(c4, 32);
        INS5(c0, c1, c2, c3, c4, o0); INS5(c0, c1, c2, c3, c4, o1);
        INS5(c0, c1, c2, c3, c4, o2); INS5(c0, c1, c2, c3, c4, o3);
        INS5(c0, c1, c2, c3, c4, o4);
    }
    if (h == 0) {
        float* p = pstats + ((size_t)ch * N_ROWS + i_laneA) * 8;
        p[0] = sumA; p[1] = a0; p[2] = a1; p[3] = a2; p[4] = a3; p[5] = a4;
        p[6] = 0.f; p[7] = 0.f;
        float* q = pstats + ((size_t)ch * N_ROWS + i_laneB) * 8;
        q[0] = sumB; q[1] = c0; q[2] = c1; q[3] = c2; q[4] = c3; q[5] = c4;
        q[6] = 0.f; q[7] = 0.f;
    }
}

// ---------------- K3: per-row merge of 16 chunk partials ----------------
__global__ __launch_bounds__(128) void reduce1(const float* __restrict__ pstats,
                                               float* __restrict__ partial) {
    int row = blockIdx.x * 128 + threadIdx.x;
    float S = 0.f;
    float b0 = NEG_BIG, b1 = NEG_BIG, b2 = NEG_BIG, b3 = NEG_BIG, b4 = NEG_BIG;
#pragma unroll
    for (int c = 0; c < NCHUNK; ++c) {
        const float* p = pstats + ((size_t)c * N_ROWS + row) * 8;
        S += p[0];
        float v0 = p[1], v1 = p[2], v2 = p[3], v3 = p[4], v4 = p[5];
        INS5(b0, b1, b2, b3, b4, v0); INS5(b0, b1, b2, b3, b4, v1);
        INS5(b0, b1, b2, b3, b4, v2); INS5(b0, b1, b2, b3, b4, v3);
        INS5(b0, b1, b2, b3, b4, v4);
    }
    float e0, e1, e2, e3, e4;
    EXPRAW(e0, b0); EXPRAW(e1, b1); EXPRAW(e2, b2); EXPRAW(e3, b3); EXPRAW(e4, b4);
    float S5 = e0 + e1 + e2 + e3 + e4;
    float loss = __logf(S) - __logf(S5);
#pragma unroll
    for (int m = 1; m < 64; m <<= 1) loss += __shfl_xor(loss, m);
    __shared__ float rr[2];
    if ((threadIdx.x & 63) == 0) rr[threadIdx.x >> 6] = loss;
    __syncthreads();
    if (threadIdx.x == 0) partial[blockIdx.x] = rr[0] + rr[1];
}

// ---------------- K4: final mean ----------------
__global__ void reduce2(const float* __restrict__ partial, float* __restrict__ out) {
    float v = partial[threadIdx.x];   // 64 partials
#pragma unroll
    for (int m = 1; m < 64; m <<= 1) v += __shfl_xor(v, m);
    if (threadIdx.x == 0) out[0] = v * (1.0f / N_ROWS);
}

extern "C" void kernel_launch(void* const* d_in, const int* in_sizes, int n_in,
                              void* d_out, int out_size, void* d_ws, size_t ws_size,
                              hipStream_t stream) {
    const float* z = (const float*)d_in[0];
    float* out = (float*)d_out;
    uint8_t* zn4   = (uint8_t*)d_ws;                                     // 4 MB
    uint8_t* sbq   = (uint8_t*)d_ws + (size_t)4 * 1024 * 1024;           // 256 KB
    float* pstats  = (float*)((char*)d_ws + (size_t)4608 * 1024);        // 4 MB
    float* partial = (float*)((char*)d_ws + (size_t)13 * 1024 * 1024);   // 256 B

    norm_kernel<<<N_ROWS / 4, 256, 0, stream>>>(z, zn4, sbq);
    sim_kernel<<<32 * NCHUNK, 256, 0, stream>>>(zn4, sbq, pstats);
    reduce1<<<N_ROWS / 128, 128, 0, stream>>>(pstats, partial);
    reduce2<<<1, 64, 0, stream>>>(partial, out);
}